// Round 7
// baseline (186.617 us; speedup 1.0000x reference)
//
#include <hip/hip_runtime.h>

namespace {
constexpr int S = 1024;
constexpr int H = 512;
constexpr int W = 512;
constexpr int B = 32;
constexpr int OFF = 256; // (S-H)/2 = (S-W)/2

__device__ __forceinline__ int refl(int i) {
    // jnp.mod(i, 2S) with 2S=2048 (pow2): bitmask gives the nonneg residue.
    int m = i & (2 * S - 1);
    return (m < S) ? m : (2 * S - 1 - m);
}

__device__ __forceinline__ bool stripe(int i, int start, int gb, int len, int n, float inv_gb) {
    int d = i - start;
    if (d < 0) return false;
    // exact integer div by runtime gb: float estimate + one-step fixup
    int q = (int)((float)d * inv_gb);
    int r = d - q * gb;
    if (r < 0)        { r += gb; --q; }
    else if (r >= gb) { r -= gb; ++q; }
    return (r < len) && (q < n);
}

__global__ __launch_bounds__(256) void gridmask_kernel(
    const float* __restrict__ images,
    const float* __restrict__ angles,
    const int* __restrict__ gridblock,
    const int* __restrict__ start1,
    const int* __restrict__ start2,
    float* __restrict__ out)
{
    __shared__ float rowt[1024];
    __shared__ float colt[1024];

    const int tid = threadIdx.x;
    const int blk = blockIdx.x;              // 2048 blocks; 64 per image
    const int b   = blk >> 6;                // block-uniform batch index
    const int pix_base = (blk & 63) << 12;   // 4096 px per block

    const size_t fbase = (size_t)blk * 12288; // 4096 px * 3 ch
    const float4* __restrict__ gin4  = (const float4*)(images + fbase);
    float4* __restrict__       gout4 = (float4*)(out + fbase);

    // ---- issue ALL 12 image loads up front: HBM latency overlaps mask math ----
    float4 px[12];
#pragma unroll
    for (int g = 0; g < 4; ++g) {
        const int v4 = (g << 8) * 3 + tid * 3; // float4 index of this group's 48B
#pragma unroll
        for (int j = 0; j < 3; ++j) px[g * 3 + j] = gin4[v4 + j];
    }

    // ---- per-image scalars ----
    const float ang = angles[b];
    const int gb = gridblock[b];
    const int s1 = start1[b];
    const int s2 = start2[b];

    const float gbf = (float)gb;
    // match numpy's two-step f32 rounding exactly: no FMA contraction
    int len = (int)(__fadd_rn(__fmul_rn(gbf, 0.6f), 0.5f));
    len = min(max(len, 1), gb - 1);
    const int n = S / gb;
    const float inv_gb = 1.0f / gbf;

    // ---- stripe tables as 0.0/1.0 floats (integer logic identical to ref) ----
    const int i0 = tid << 2;
#pragma unroll
    for (int k = 0; k < 4; ++k) {
        rowt[i0 + k] = stripe(i0 + k, s1, gb, len, n, inv_gb) ? 1.0f : 0.0f;
        colt[i0 + k] = stripe(i0 + k, s2, gb, len, n, inv_gb) ? 1.0f : 0.0f;
    }

    float sn, cs;
    sincosf(ang, &sn, &cs);
    const float c = (float)(S - 1) * 0.5f; // 511.5

    __syncthreads();

#pragma unroll
    for (int g = 0; g < 4; ++g) {
        const int lp   = (g << 10) + (tid << 2);  // local pixel [0,4096)
        const int gpix = pix_base + lp;
        const int y    = gpix >> 9;               // row [0,512)
        const int x    = gpix & 511;              // col, multiple of 4

        const float Y = (float)(y + OFF) - c;
        float m[4];
#pragma unroll
        for (int i = 0; i < 4; ++i) {
            const float X  = (float)(x + i + OFF) - c;
            const float sx =  cs * X + sn * Y + c;
            const float sy =  cs * Y - sn * X + c;
            const float x0f = floorf(sx);
            const float y0f = floorf(sy);
            const float fx = sx - x0f;
            const float fy = sy - y0f;
            const int x0i = (int)x0f;
            const int y0i = (int)y0f;
            const int x0r = refl(x0i), x1r = refl(x0i + 1);
            const int y0r = refl(y0i), y1r = refl(y0i + 1);
            const float r0 = rowt[y0r], r1 = rowt[y1r];
            const float c0 = colt[x0r], c1 = colt[x1r];
            // taps are 0/1: sum_ij w_ij*(r_i|c_j) == ry + cx - ry*cx
            const float ry = r0 + fy * (r1 - r0);
            const float cx = c0 + fx * (c1 - c0);
            m[i] = ry + cx - ry * cx;
        }

        const float4 p0 = px[g * 3 + 0];
        const float4 p1 = px[g * 3 + 1];
        const float4 p2 = px[g * 3 + 2];
        float4 o0, o1, o2;
        o0.x = p0.x * m[0]; o0.y = p0.y * m[0]; o0.z = p0.z * m[0]; o0.w = p0.w * m[1];
        o1.x = p1.x * m[1]; o1.y = p1.y * m[1]; o1.z = p1.z * m[2]; o1.w = p1.w * m[2];
        o2.x = p2.x * m[2]; o2.y = p2.y * m[3]; o2.z = p2.z * m[3]; o2.w = p2.w * m[3];

        const int v4 = (g << 8) * 3 + tid * 3;
        gout4[v4 + 0] = o0;
        gout4[v4 + 1] = o1;
        gout4[v4 + 2] = o2;
    }
}
} // namespace

extern "C" void kernel_launch(void* const* d_in, const int* in_sizes, int n_in,
                              void* d_out, int out_size, void* d_ws, size_t ws_size,
                              hipStream_t stream) {
    const float* images    = (const float*)d_in[0];
    const float* angles    = (const float*)d_in[1];
    const int*   gridblock = (const int*)d_in[2];
    const int*   start1    = (const int*)d_in[3];
    const int*   start2    = (const int*)d_in[4];
    float* outp = (float*)d_out;

    const int blocks = B * H * W / 4096; // 2048 blocks x 256 threads, 16 px/thread
    gridmask_kernel<<<blocks, 256, 0, stream>>>(images, angles, gridblock, start1, start2, outp);
}